// Round 1
// baseline (1517.701 us; speedup 1.0000x reference)
//
#include <hip/hip_runtime.h>
#include <cstdint>
#include <cstddef>

#define DD 64
#define EV 16

__device__ __forceinline__ float sigmoidf_(float x) {
    return 1.0f / (1.0f + __expf(-x));
}
__device__ __forceinline__ float tanh_fast(float x) {
    float ax = fabsf(x);
    float t = 1.0f - 2.0f / (1.0f + __expf(2.0f * ax));
    return copysignf(t, x);
}

// winner[] lives in the out2 region reinterpreted as int
__global__ void k_init(int* __restrict__ winner, int num_nodes) {
    int i = blockIdx.x * blockDim.x + threadIdx.x;
    if (i < num_nodes) winner[i] = -1;
}

__global__ void k_vote(const int* __restrict__ ids, int* __restrict__ winner, int n) {
    int i = blockIdx.x * blockDim.x + threadIdx.x;
    if (i < n) atomicMax(&winner[ids[i]], i);
}

// 4 waves / block; each wave handles EV events; lane = output dim d (0..63)
__global__ __launch_bounds__(256) void k_gru(
    const int* __restrict__ ids,
    const float* __restrict__ emb,
    const float* __restrict__ ts,
    const float* __restrict__ mem,
    const float* __restrict__ lut,
    const float* __restrict__ Wt,    // [64]
    const float* __restrict__ bt,    // [64]
    const float* __restrict__ Wih,   // [192,64] row-major
    const float* __restrict__ Whh,   // [192,64]
    const float* __restrict__ bih,   // [192]
    const float* __restrict__ bhh,   // [192]
    float* __restrict__ out0,        // [N,64]
    int n)
{
    __shared__ __align__(16) float xs[4][EV][DD];
    __shared__ __align__(16) float hs[4][EV][DD];

    const int w    = threadIdx.x >> 6;
    const int lane = threadIdx.x & 63;
    const long gw   = (long)blockIdx.x * 4 + w;
    const long base = gw * EV;

    const float wtd = Wt[lane];
    const float btd = bt[lane];

    // ---- stage x and h tiles into LDS ----
    for (int e = 0; e < EV; ++e) {
        long ev = base + e;
        if (ev < n) {
            int id = ids[ev];
            float dt = ts[ev] - lut[id];
            float x = emb[(size_t)ev * DD + lane] + dt * wtd + btd;
            float h = mem[(size_t)id * DD + lane];
            xs[w][e][lane] = x;
            hs[w][e][lane] = h;
        }
    }
    __syncthreads();

    // ---- GEMM: lane d computes 6 dot products (rows d, d+64, d+128 of Wih/Whh)
    //      for EV events simultaneously ----
    float air[EV] = {}, aiz[EV] = {}, ain[EV] = {};
    float ahr[EV] = {}, ahz[EV] = {}, ahn[EV] = {};

    const float4* __restrict__ Wih4 = (const float4*)Wih;  // row d -> Wih4[d*16 + k4]
    const float4* __restrict__ Whh4 = (const float4*)Whh;
    const int d = lane;

    #pragma unroll 1
    for (int k4 = 0; k4 < 16; ++k4) {
        float4 wr = Wih4[(size_t)d * 16 + k4];
        float4 wz = Wih4[(size_t)(d + 64) * 16 + k4];
        float4 wn = Wih4[(size_t)(d + 128) * 16 + k4];
        float4 ur = Whh4[(size_t)d * 16 + k4];
        float4 uz = Whh4[(size_t)(d + 64) * 16 + k4];
        float4 un = Whh4[(size_t)(d + 128) * 16 + k4];
        #pragma unroll
        for (int e = 0; e < EV; ++e) {
            float4 xv = *(const float4*)&xs[w][e][k4 * 4];  // uniform addr -> broadcast
            float4 hv = *(const float4*)&hs[w][e][k4 * 4];
            air[e] += xv.x * wr.x + xv.y * wr.y + xv.z * wr.z + xv.w * wr.w;
            aiz[e] += xv.x * wz.x + xv.y * wz.y + xv.z * wz.z + xv.w * wz.w;
            ain[e] += xv.x * wn.x + xv.y * wn.y + xv.z * wn.z + xv.w * wn.w;
            ahr[e] += hv.x * ur.x + hv.y * ur.y + hv.z * ur.z + hv.w * ur.w;
            ahz[e] += hv.x * uz.x + hv.y * uz.y + hv.z * uz.z + hv.w * uz.w;
            ahn[e] += hv.x * un.x + hv.y * un.y + hv.z * un.z + hv.w * un.w;
        }
    }

    // ---- epilogue: gates + output ----
    const float bir = bih[d],        bhr = bhh[d];
    const float biz = bih[64 + d],   bhz = bhh[64 + d];
    const float bin = bih[128 + d],  bhn = bhh[128 + d];

    for (int e = 0; e < EV; ++e) {
        long ev = base + e;
        if (ev < n) {
            float r  = sigmoidf_(air[e] + ahr[e] + bir + bhr);
            float z  = sigmoidf_(aiz[e] + ahz[e] + biz + bhz);
            float nn = tanh_fast(ain[e] + bin + r * (ahn[e] + bhn));
            float h  = hs[w][e][d];
            out0[(size_t)ev * DD + d] = (1.0f - z) * nn + z * h;
        }
    }
}

// out1[n] = winner>=0 ? updated_memory[winner[n]] : node_memory[n]   (float4 granularity)
__global__ void k_scatter_mem(const int* __restrict__ winner,
                              const float4* __restrict__ mem4,
                              const float4* __restrict__ out04,
                              float4* __restrict__ out14,
                              int num_nodes)
{
    int idx = blockIdx.x * blockDim.x + threadIdx.x;
    if (idx >= num_nodes * 16) return;
    int nidx = idx >> 4;
    int c    = idx & 15;
    int wv = winner[nidx];
    out14[idx] = (wv >= 0) ? out04[(size_t)wv * 16 + c] : mem4[idx];
}

// out2[n] = winner>=0 ? timestamps[winner[n]] : last_update_time[n]
// winner is stored IN out2 (as int); each thread reads its own slot then overwrites it.
__global__ void k_scatter_time(float* out2,
                               const float* __restrict__ ts,
                               const float* __restrict__ lut,
                               int num_nodes)
{
    int i = blockIdx.x * blockDim.x + threadIdx.x;
    if (i < num_nodes) {
        int wv = reinterpret_cast<const int*>(out2)[i];
        out2[i] = (wv >= 0) ? ts[wv] : lut[i];
    }
}

extern "C" void kernel_launch(void* const* d_in, const int* in_sizes, int n_in,
                              void* d_out, int out_size, void* d_ws, size_t ws_size,
                              hipStream_t stream) {
    const int*   ids = (const int*)  d_in[0];
    const float* emb = (const float*)d_in[1];
    const float* ts  = (const float*)d_in[2];
    const float* mem = (const float*)d_in[3];
    const float* lut = (const float*)d_in[4];
    const float* Wt  = (const float*)d_in[5];
    const float* bt  = (const float*)d_in[6];
    const float* Wih = (const float*)d_in[7];
    const float* Whh = (const float*)d_in[8];
    const float* bih = (const float*)d_in[9];
    const float* bhh = (const float*)d_in[10];

    const int N         = in_sizes[0];
    const int NUM_NODES = in_sizes[4];

    float* out0 = (float*)d_out;                       // [N,64]
    float* out1 = out0 + (size_t)N * DD;               // [NUM_NODES,64]
    float* out2 = out1 + (size_t)NUM_NODES * DD;       // [NUM_NODES]
    int*   winner = (int*)out2;                        // reuse out2 region as scratch

    // 1) winner init + vote
    k_init<<<(NUM_NODES + 255) / 256, 256, 0, stream>>>(winner, NUM_NODES);
    k_vote<<<(N + 255) / 256, 256, 0, stream>>>(ids, winner, N);

    // 2) GRU -> out0
    int evPerBlock = 4 * EV;
    int gruBlocks  = (N + evPerBlock - 1) / evPerBlock;
    k_gru<<<gruBlocks, 256, 0, stream>>>(ids, emb, ts, mem, lut, Wt, bt,
                                         Wih, Whh, bih, bhh, out0, N);

    // 3) scatter memory rows -> out1
    long vec = (long)NUM_NODES * 16;
    k_scatter_mem<<<(int)((vec + 255) / 256), 256, 0, stream>>>(
        winner, (const float4*)mem, (const float4*)out0, (float4*)out1, NUM_NODES);

    // 4) scatter timestamps -> out2 (overwrites winner storage, self-slot RMW)
    k_scatter_time<<<(NUM_NODES + 255) / 256, 256, 0, stream>>>(out2, ts, lut, NUM_NODES);
}

// Round 2
// 464.753 us; speedup vs baseline: 3.2656x; 3.2656x over previous
//
#include <hip/hip_runtime.h>
#include <cstdint>
#include <cstddef>

#define DD 64

typedef float  f32x4 __attribute__((ext_vector_type(4)));
typedef short  s16x8 __attribute__((ext_vector_type(8)));

__device__ __forceinline__ unsigned short f2bf(float v) {
    union { float f; unsigned u; } x; x.f = v;
    unsigned r = x.u + 0x7FFF + ((x.u >> 16) & 1);
    return (unsigned short)(r >> 16);
}
__device__ __forceinline__ float bf2f(unsigned short b) {
    union { float f; unsigned u; } x; x.u = ((unsigned)b) << 16;
    return x.f;
}
__device__ __forceinline__ float sigmoidf_(float x) {
    return 1.0f / (1.0f + __expf(-x));
}
__device__ __forceinline__ float tanh_fast(float x) {
    float ax = fabsf(x);
    float t = 1.0f - 2.0f / (1.0f + __expf(2.0f * ax));
    return copysignf(t, x);
}
__device__ __forceinline__ f32x4 MFMA(f32x4 c, s16x8 a, s16x8 b) {
    return __builtin_amdgcn_mfma_f32_16x16x32_bf16(a, b, c, 0, 0, 0);
}

// ---------------- winner voting (winner[] lives in out2 region) ----------------
__global__ void k_init(int* __restrict__ winner, int num_nodes) {
    int i = blockIdx.x * blockDim.x + threadIdx.x;
    if (i < num_nodes) winner[i] = -1;
}
__global__ void k_vote(const int* __restrict__ ids, int* __restrict__ winner, int n) {
    int i = blockIdx.x * blockDim.x + threadIdx.x;
    if (i < n) atomicMax(&winner[ids[i]], i);
}

// ---------------- build B fragments (hi/lo split bf16) into ws ----------------
// Conceptual B[128][256]: cols 0..63 r-gate (K: x then h), 64..127 z-gate,
// 128..191 i_n (x only), 192..255 h_n (h only).
// Fragment f = g*4+s (g=tile 0..15, s=K-step 0..3); lane l holds
// B[s*32+(l>>4)*8+j][g*16+(l&15)], j=0..7, packed 8 bf16 = 16B.
__global__ void k_prep(const float* __restrict__ Wih, const float* __restrict__ Whh,
                       unsigned short* __restrict__ bhi, unsigned short* __restrict__ blo)
{
    int f = blockIdx.x;        // 0..63
    int l = threadIdx.x;       // 0..63
    int g = f >> 2, s = f & 3;
    int c = g * 16 + (l & 15);
    int grp = c >> 6, d = c & 63;
    int kbase = s * 32 + (l >> 4) * 8;
    int row = (grp == 0) ? d : (grp == 1) ? 64 + d : 128 + d;

    s16x8 hv, lv;
    for (int j = 0; j < 8; ++j) {
        int k = kbase + j;
        float v;
        if (grp <= 1)      v = (k < 64) ? Wih[row * 64 + k] : Whh[row * 64 + (k - 64)];
        else if (grp == 2) v = (k < 64) ? Wih[row * 64 + k] : 0.0f;
        else               v = (k < 64) ? 0.0f : Whh[row * 64 + (k - 64)];
        unsigned short h = f2bf(v);
        float r = v - bf2f(h);
        hv[j] = (short)h;
        lv[j] = (short)f2bf(r);
    }
    size_t off = ((size_t)f * 64 + l);
    ((s16x8*)bhi)[off] = hv;
    ((s16x8*)blo)[off] = lv;
}

// ---------------- main GRU kernel (MFMA split-bf16) ----------------
__global__ __launch_bounds__(256, 2) void k_gru(
    const int* __restrict__ ids,
    const float* __restrict__ emb,
    const float* __restrict__ ts,
    const float* __restrict__ mem,
    const float* __restrict__ lut,
    const float* __restrict__ Wt,
    const float* __restrict__ bt,
    const float* __restrict__ bih,
    const float* __restrict__ bhh,
    const unsigned short* __restrict__ bhi,
    const unsigned short* __restrict__ blo,
    const int* __restrict__ winner,
    float* __restrict__ out0,
    float* __restrict__ out1,
    int n, int nchunks)
{
    __shared__ unsigned short xhh[64][136];   // hi plane: [event][k], k<64 x, k>=64 h
    __shared__ unsigned short xhl[64][136];   // lo plane
    __shared__ int sid[64];
    __shared__ int swin[64];

    const int w    = threadIdx.x >> 6;
    const int l    = threadIdx.x & 63;
    const int col  = l & 15;
    const int rowg = l >> 4;
    const int d    = w * 16 + col;      // output dim this lane owns in epilogue

    const float wtl = Wt[l], btl = bt[l];           // staging (lane = dim)
    const float bR  = bih[d] + bhh[d];
    const float bZ  = bih[64 + d] + bhh[64 + d];
    const float bIN = bih[128 + d];
    const float bHN = bhh[128 + d];

    // persistent B fragments for this wave's 4 gate tiles
    const s16x8* H = (const s16x8*)bhi;
    const s16x8* L = (const s16x8*)blo;
    s16x8 BRh[4], BRl[4], BZh[4], BZl[4], BIh[2], BIl[2], BHh[2], BHl[2];
    for (int s = 0; s < 4; ++s) {
        BRh[s] = H[(size_t)((w)      * 4 + s) * 64 + l];
        BRl[s] = L[(size_t)((w)      * 4 + s) * 64 + l];
        BZh[s] = H[(size_t)((4 + w)  * 4 + s) * 64 + l];
        BZl[s] = L[(size_t)((4 + w)  * 4 + s) * 64 + l];
    }
    for (int s = 0; s < 2; ++s) {
        BIh[s] = H[(size_t)((8 + w)  * 4 + s)       * 64 + l];
        BIl[s] = L[(size_t)((8 + w)  * 4 + s)       * 64 + l];
        BHh[s] = H[(size_t)((12 + w) * 4 + (2 + s)) * 64 + l];
        BHl[s] = L[(size_t)((12 + w) * 4 + (2 + s)) * 64 + l];
    }

    for (int ch = blockIdx.x; ch < nchunks; ch += gridDim.x) {
        const long base = (long)ch * 64;

        // ---- stage this wave's 16 events into LDS (hi/lo bf16) ----
        #pragma unroll 4
        for (int e = 0; e < 16; ++e) {
            long ev = base + w * 16 + e;
            int  r  = w * 16 + e;
            float x = 0.f, h = 0.f;
            if (ev < n) {
                int id   = ids[ev];
                float dt = ts[ev] - lut[id];
                x = emb[(size_t)ev * 64 + l] + dt * wtl + btl;
                h = mem[(size_t)id * 64 + l];
                if (l == 0) { sid[r] = id; swin[r] = (winner[id] == (int)ev); }
            } else if (l == 0) { sid[r] = 0; swin[r] = 0; }
            unsigned short xh_ = f2bf(x); float xr = x - bf2f(xh_);
            unsigned short hh_ = f2bf(h); float hr = h - bf2f(hh_);
            xhh[r][l]      = xh_;        xhl[r][l]      = f2bf(xr);
            xhh[r][64 + l] = hh_;        xhl[r][64 + l] = f2bf(hr);
        }
        __syncthreads();

        // ---- 4 M-tiles of 16 events each ----
        for (int mt = 0; mt < 4; ++mt) {
            const int arow = mt * 16 + col;
            const int k0   = rowg * 8;
            s16x8 Ah[4], Al[4];
            #pragma unroll
            for (int s = 0; s < 4; ++s) {
                Ah[s] = *(const s16x8*)&xhh[arow][s * 32 + k0];
                Al[s] = *(const s16x8*)&xhl[arow][s * 32 + k0];
            }
            f32x4 aR = {0,0,0,0}, aZ = {0,0,0,0}, aI = {0,0,0,0}, aH = {0,0,0,0};
            #pragma unroll
            for (int s = 0; s < 4; ++s) {
                aR = MFMA(aR, Ah[s], BRh[s]);
                aR = MFMA(aR, Ah[s], BRl[s]);
                aR = MFMA(aR, Al[s], BRh[s]);
                aZ = MFMA(aZ, Ah[s], BZh[s]);
                aZ = MFMA(aZ, Ah[s], BZl[s]);
                aZ = MFMA(aZ, Al[s], BZh[s]);
            }
            aI = MFMA(aI, Ah[0], BIh[0]); aI = MFMA(aI, Ah[0], BIl[0]); aI = MFMA(aI, Al[0], BIh[0]);
            aI = MFMA(aI, Ah[1], BIh[1]); aI = MFMA(aI, Ah[1], BIl[1]); aI = MFMA(aI, Al[1], BIh[1]);
            aH = MFMA(aH, Ah[2], BHh[0]); aH = MFMA(aH, Ah[2], BHl[0]); aH = MFMA(aH, Al[2], BHh[0]);
            aH = MFMA(aH, Ah[3], BHh[1]); aH = MFMA(aH, Ah[3], BHl[1]); aH = MFMA(aH, Al[3], BHh[1]);

            // ---- epilogue: gates, output, fused winner scatter ----
            #pragma unroll
            for (int r = 0; r < 4; ++r) {
                int  eloc = mt * 16 + rowg * 4 + r;
                long ev   = base + eloc;
                if (ev < n) {
                    float rr = sigmoidf_(aR[r] + bR);
                    float zz = sigmoidf_(aZ[r] + bZ);
                    float nn = tanh_fast(aI[r] + bIN + rr * (aH[r] + bHN));
                    float hv = bf2f(xhh[eloc][64 + d]) + bf2f(xhl[eloc][64 + d]);
                    float o  = (1.f - zz) * nn + zz * hv;
                    out0[(size_t)ev * 64 + d] = o;
                    if (swin[eloc]) out1[(size_t)sid[eloc] * 64 + d] = o;
                }
            }
        }
        __syncthreads();
    }
}

// out1 rows for untouched nodes (winner<0): copy from node_memory
__global__ void k_fill(const int* __restrict__ winner,
                       const float4* __restrict__ mem4,
                       float4* __restrict__ out14,
                       int num_nodes)
{
    int idx = blockIdx.x * blockDim.x + threadIdx.x;
    if (idx >= num_nodes * 16) return;
    int nidx = idx >> 4;
    if (winner[nidx] < 0) out14[idx] = mem4[idx];
}

// out2[n] = winner>=0 ? ts[winner] : lut[n]; winner stored IN out2, self-slot RMW
__global__ void k_time(float* out2,
                       const float* __restrict__ ts,
                       const float* __restrict__ lut,
                       int num_nodes)
{
    int i = blockIdx.x * blockDim.x + threadIdx.x;
    if (i < num_nodes) {
        int wv = reinterpret_cast<const int*>(out2)[i];
        out2[i] = (wv >= 0) ? ts[wv] : lut[i];
    }
}

extern "C" void kernel_launch(void* const* d_in, const int* in_sizes, int n_in,
                              void* d_out, int out_size, void* d_ws, size_t ws_size,
                              hipStream_t stream) {
    const int*   ids = (const int*)  d_in[0];
    const float* emb = (const float*)d_in[1];
    const float* ts  = (const float*)d_in[2];
    const float* mem = (const float*)d_in[3];
    const float* lut = (const float*)d_in[4];
    const float* Wt  = (const float*)d_in[5];
    const float* bt  = (const float*)d_in[6];
    const float* Wih = (const float*)d_in[7];
    const float* Whh = (const float*)d_in[8];
    const float* bih = (const float*)d_in[9];
    const float* bhh = (const float*)d_in[10];

    const int N         = in_sizes[0];
    const int NUM_NODES = in_sizes[4];

    float* out0 = (float*)d_out;                    // [N,64]
    float* out1 = out0 + (size_t)N * DD;            // [NUM_NODES,64]
    float* out2 = out1 + (size_t)NUM_NODES * DD;    // [NUM_NODES]
    int*   winner = (int*)out2;

    unsigned short* bfragH = (unsigned short*)d_ws;            // 64 KB
    unsigned short* bfragL = bfragH + 64 * 64 * 8;             // 64 KB

    k_init<<<(NUM_NODES + 255) / 256, 256, 0, stream>>>(winner, NUM_NODES);
    k_vote<<<(N + 255) / 256, 256, 0, stream>>>(ids, winner, N);
    k_prep<<<64, 64, 0, stream>>>(Wih, Whh, bfragH, bfragL);

    int nchunks = (N + 63) / 64;
    int grid = 2048;
    if (grid > nchunks) grid = nchunks;
    k_gru<<<grid, 256, 0, stream>>>(ids, emb, ts, mem, lut, Wt, bt, bih, bhh,
                                    bfragH, bfragL, winner, out0, out1, N, nchunks);

    long vec = (long)NUM_NODES * 16;
    k_fill<<<(int)((vec + 255) / 256), 256, 0, stream>>>(
        winner, (const float4*)mem, (float4*)out1, NUM_NODES);

    k_time<<<(NUM_NODES + 255) / 256, 256, 0, stream>>>(out2, ts, lut, NUM_NODES);
}

// Round 3
// 319.786 us; speedup vs baseline: 4.7460x; 1.4533x over previous
//
#include <hip/hip_runtime.h>
#include <cstdint>
#include <cstddef>

#define DD 64

typedef float    f32x4 __attribute__((ext_vector_type(4)));
typedef _Float16 f16x8 __attribute__((ext_vector_type(8)));
typedef _Float16 f16x4 __attribute__((ext_vector_type(4)));

__device__ __forceinline__ float sigmoidf_(float x) {
    return 1.0f / (1.0f + __expf(-x));
}
__device__ __forceinline__ float tanh_fast(float x) {
    float ax = fabsf(x);
    float t = 1.0f - 2.0f / (1.0f + __expf(2.0f * ax));
    return copysignf(t, x);
}
__device__ __forceinline__ f32x4 MFMA(f32x4 c, f16x8 a, f16x8 b) {
    return __builtin_amdgcn_mfma_f32_16x16x32_f16(a, b, c, 0, 0, 0);
}

// ---------------- winner voting (winner[] lives in out2 region) ----------------
__global__ void k_init(int* __restrict__ winner, int num_nodes) {
    int i = blockIdx.x * blockDim.x + threadIdx.x;
    if (i < num_nodes) winner[i] = -1;
}
__global__ void k_vote(const int* __restrict__ ids, int* __restrict__ winner, int n) {
    int i = blockIdx.x * blockDim.x + threadIdx.x;
    if (i < n) atomicMax(&winner[ids[i]], i);
}

// ---------------- build B fragments (hi/lo split fp16) into ws ----------------
// Conceptual B[128][256]: cols 0..63 r-gate (K: x then h), 64..127 z-gate,
// 128..191 i_n (x only), 192..255 h_n (h only).
// Fragment f = g*4+s (g=tile 0..15, s=K-step 0..3); lane l holds
// B[s*32+(l>>4)*8+j][g*16+(l&15)], j=0..7, packed 8 fp16 = 16B.
__global__ void k_prep(const float* __restrict__ Wih, const float* __restrict__ Whh,
                       _Float16* __restrict__ bhi, _Float16* __restrict__ blo)
{
    int f = blockIdx.x;        // 0..63
    int l = threadIdx.x;       // 0..63
    int g = f >> 2, s = f & 3;
    int c = g * 16 + (l & 15);
    int grp = c >> 6, d = c & 63;
    int kbase = s * 32 + (l >> 4) * 8;
    int row = (grp == 0) ? d : (grp == 1) ? 64 + d : 128 + d;

    f16x8 hv, lv;
    for (int j = 0; j < 8; ++j) {
        int k = kbase + j;
        float v;
        if (grp <= 1)      v = (k < 64) ? Wih[row * 64 + k] : Whh[row * 64 + (k - 64)];
        else if (grp == 2) v = (k < 64) ? Wih[row * 64 + k] : 0.0f;
        else               v = (k < 64) ? 0.0f : Whh[row * 64 + (k - 64)];
        _Float16 h = (_Float16)v;
        hv[j] = h;
        lv[j] = (_Float16)(v - (float)h);
    }
    size_t off = ((size_t)f * 64 + l);
    ((f16x8*)bhi)[off] = hv;
    ((f16x8*)blo)[off] = lv;
}

// ---------------- main GRU kernel (MFMA split-fp16) ----------------
__global__ __launch_bounds__(256, 3) void k_gru(
    const int* __restrict__ ids,
    const float* __restrict__ emb,
    const float* __restrict__ ts,
    const float* __restrict__ mem,
    const float* __restrict__ lut,
    const float* __restrict__ Wt,
    const float* __restrict__ bt,
    const float* __restrict__ bih,
    const float* __restrict__ bhh,
    const _Float16* __restrict__ bhi,
    const _Float16* __restrict__ blo,
    const int* __restrict__ winner,
    float* __restrict__ out0,
    float* __restrict__ out1,
    int n, int nchunks)
{
    __shared__ _Float16 xhh[64][136];   // hi plane: [event][k], k<64 x, k>=64 h
    __shared__ _Float16 xhl[64][136];   // lo plane
    __shared__ int sid[64];
    __shared__ int swin[64];

    const int w    = threadIdx.x >> 6;
    const int l    = threadIdx.x & 63;
    const int col  = l & 15;
    const int rowg = l >> 4;
    const int d    = w * 16 + col;      // output dim this lane owns in epilogue

    const float bR  = bih[d] + bhh[d];
    const float bZ  = bih[64 + d] + bhh[64 + d];
    const float bIN = bih[128 + d];
    const float bHN = bhh[128 + d];

    // persistent B fragments for this wave's 4 gate tiles
    const f16x8* H = (const f16x8*)bhi;
    const f16x8* L = (const f16x8*)blo;
    f16x8 BRh[4], BRl[4], BZh[4], BZl[4], BIh[2], BIl[2], BHh[2], BHl[2];
    for (int s = 0; s < 4; ++s) {
        BRh[s] = H[(size_t)((w)      * 4 + s) * 64 + l];
        BRl[s] = L[(size_t)((w)      * 4 + s) * 64 + l];
        BZh[s] = H[(size_t)((4 + w)  * 4 + s) * 64 + l];
        BZl[s] = L[(size_t)((4 + w)  * 4 + s) * 64 + l];
    }
    for (int s = 0; s < 2; ++s) {
        BIh[s] = H[(size_t)((8 + w)  * 4 + s)       * 64 + l];
        BIl[s] = L[(size_t)((8 + w)  * 4 + s)       * 64 + l];
        BHh[s] = H[(size_t)((12 + w) * 4 + (2 + s)) * 64 + l];
        BHl[s] = L[(size_t)((12 + w) * 4 + (2 + s)) * 64 + l];
    }

    const float4 wt4 = ((const float4*)Wt)[col];
    const float4 bt4 = ((const float4*)bt)[col];

    for (int ch = blockIdx.x; ch < nchunks; ch += gridDim.x) {
        const long base = (long)ch * 64;

        // ---- phase A: lanes 0..15 fetch per-event scalars in parallel ----
        float dtA = 0.f; int idA = 0;
        if (l < 16) {
            long ev = base + w * 16 + l;
            int id = 0, win = 0; float dt = 0.f;
            if (ev < n) {
                id = ids[ev];
                dt = ts[ev] - lut[id];
                win = (winner[id] == (int)ev) ? 1 : 0;
            }
            idA = id; dtA = dt;
            sid[w * 16 + l] = id;
            swin[w * 16 + l] = win;
        }

        // ---- phase B: 4 iterations of float4 loads; each lane does 4 dims of 1 event ----
        #pragma unroll
        for (int it = 0; it < 4; ++it) {
            int  e_loc = it * 4 + rowg;           // 0..15
            int  r     = w * 16 + e_loc;
            long ev    = base + r;
            int   id = __shfl(idA, e_loc);
            float dt = __shfl(dtA, e_loc);
            float4 xv = {0.f, 0.f, 0.f, 0.f};
            float4 hv = {0.f, 0.f, 0.f, 0.f};
            if (ev < n) {
                xv = ((const float4*)emb)[(size_t)ev * 16 + col];
                hv = ((const float4*)mem)[(size_t)id * 16 + col];
                xv.x = fmaf(dt, wt4.x, xv.x + bt4.x);
                xv.y = fmaf(dt, wt4.y, xv.y + bt4.y);
                xv.z = fmaf(dt, wt4.z, xv.z + bt4.z);
                xv.w = fmaf(dt, wt4.w, xv.w + bt4.w);
            }
            f16x4 xh, xl, hh, hl;
            {
                _Float16 a;
                a = (_Float16)xv.x; xh[0] = a; xl[0] = (_Float16)(xv.x - (float)a);
                a = (_Float16)xv.y; xh[1] = a; xl[1] = (_Float16)(xv.y - (float)a);
                a = (_Float16)xv.z; xh[2] = a; xl[2] = (_Float16)(xv.z - (float)a);
                a = (_Float16)xv.w; xh[3] = a; xl[3] = (_Float16)(xv.w - (float)a);
                a = (_Float16)hv.x; hh[0] = a; hl[0] = (_Float16)(hv.x - (float)a);
                a = (_Float16)hv.y; hh[1] = a; hl[1] = (_Float16)(hv.y - (float)a);
                a = (_Float16)hv.z; hh[2] = a; hl[2] = (_Float16)(hv.z - (float)a);
                a = (_Float16)hv.w; hh[3] = a; hl[3] = (_Float16)(hv.w - (float)a);
            }
            *(f16x4*)&xhh[r][col * 4]      = xh;
            *(f16x4*)&xhl[r][col * 4]      = xl;
            *(f16x4*)&xhh[r][64 + col * 4] = hh;
            *(f16x4*)&xhl[r][64 + col * 4] = hl;
        }
        __syncthreads();

        // ---- 4 M-tiles of 16 events each ----
        for (int mt = 0; mt < 4; ++mt) {
            const int arow = mt * 16 + col;
            const int k0   = rowg * 8;
            f16x8 Ah[4], Al[4];
            #pragma unroll
            for (int s = 0; s < 4; ++s) {
                Ah[s] = *(const f16x8*)&xhh[arow][s * 32 + k0];
                Al[s] = *(const f16x8*)&xhl[arow][s * 32 + k0];
            }
            f32x4 aR = {0,0,0,0}, aZ = {0,0,0,0}, aI = {0,0,0,0}, aH = {0,0,0,0};
            #pragma unroll
            for (int s = 0; s < 4; ++s) {
                aR = MFMA(aR, Ah[s], BRh[s]);
                aR = MFMA(aR, Ah[s], BRl[s]);
                aR = MFMA(aR, Al[s], BRh[s]);
                aZ = MFMA(aZ, Ah[s], BZh[s]);
                aZ = MFMA(aZ, Ah[s], BZl[s]);
                aZ = MFMA(aZ, Al[s], BZh[s]);
            }
            aI = MFMA(aI, Ah[0], BIh[0]); aI = MFMA(aI, Ah[0], BIl[0]); aI = MFMA(aI, Al[0], BIh[0]);
            aI = MFMA(aI, Ah[1], BIh[1]); aI = MFMA(aI, Ah[1], BIl[1]); aI = MFMA(aI, Al[1], BIh[1]);
            aH = MFMA(aH, Ah[2], BHh[0]); aH = MFMA(aH, Ah[2], BHl[0]); aH = MFMA(aH, Al[2], BHh[0]);
            aH = MFMA(aH, Ah[3], BHh[1]); aH = MFMA(aH, Ah[3], BHl[1]); aH = MFMA(aH, Al[3], BHh[1]);

            // ---- epilogue: gates, output, fused winner scatter ----
            #pragma unroll
            for (int r = 0; r < 4; ++r) {
                int  eloc = mt * 16 + rowg * 4 + r;
                long ev   = base + eloc;
                if (ev < n) {
                    float rr = sigmoidf_(aR[r] + bR);
                    float zz = sigmoidf_(aZ[r] + bZ);
                    float nn = tanh_fast(aI[r] + bIN + rr * (aH[r] + bHN));
                    float hv = (float)xhh[eloc][64 + d] + (float)xhl[eloc][64 + d];
                    float o  = (1.f - zz) * nn + zz * hv;
                    out0[(size_t)ev * 64 + d] = o;
                    if (swin[eloc]) out1[(size_t)sid[eloc] * 64 + d] = o;
                }
            }
        }
        __syncthreads();
    }
}

// out1 rows for untouched nodes (winner<0): copy from node_memory
__global__ void k_fill(const int* __restrict__ winner,
                       const float4* __restrict__ mem4,
                       float4* __restrict__ out14,
                       int num_nodes)
{
    int idx = blockIdx.x * blockDim.x + threadIdx.x;
    if (idx >= num_nodes * 16) return;
    int nidx = idx >> 4;
    if (winner[nidx] < 0) out14[idx] = mem4[idx];
}

// out2[n] = winner>=0 ? ts[winner] : lut[n]; winner stored IN out2, self-slot RMW
__global__ void k_time(float* out2,
                       const float* __restrict__ ts,
                       const float* __restrict__ lut,
                       int num_nodes)
{
    int i = blockIdx.x * blockDim.x + threadIdx.x;
    if (i < num_nodes) {
        int wv = reinterpret_cast<const int*>(out2)[i];
        out2[i] = (wv >= 0) ? ts[wv] : lut[i];
    }
}

extern "C" void kernel_launch(void* const* d_in, const int* in_sizes, int n_in,
                              void* d_out, int out_size, void* d_ws, size_t ws_size,
                              hipStream_t stream) {
    const int*   ids = (const int*)  d_in[0];
    const float* emb = (const float*)d_in[1];
    const float* ts  = (const float*)d_in[2];
    const float* mem = (const float*)d_in[3];
    const float* lut = (const float*)d_in[4];
    const float* Wt  = (const float*)d_in[5];
    const float* bt  = (const float*)d_in[6];
    const float* Wih = (const float*)d_in[7];
    const float* Whh = (const float*)d_in[8];
    const float* bih = (const float*)d_in[9];
    const float* bhh = (const float*)d_in[10];

    const int N         = in_sizes[0];
    const int NUM_NODES = in_sizes[4];

    float* out0 = (float*)d_out;                    // [N,64]
    float* out1 = out0 + (size_t)N * DD;            // [NUM_NODES,64]
    float* out2 = out1 + (size_t)NUM_NODES * DD;    // [NUM_NODES]
    int*   winner = (int*)out2;

    _Float16* bfragH = (_Float16*)d_ws;             // 64 KB
    _Float16* bfragL = bfragH + 64 * 64 * 8;        // 64 KB

    k_init<<<(NUM_NODES + 255) / 256, 256, 0, stream>>>(winner, NUM_NODES);
    k_vote<<<(N + 255) / 256, 256, 0, stream>>>(ids, winner, N);
    k_prep<<<64, 64, 0, stream>>>(Wih, Whh, bfragH, bfragL);

    int nchunks = (N + 63) / 64;
    int grid = 2048;
    if (grid > nchunks) grid = nchunks;
    k_gru<<<grid, 256, 0, stream>>>(ids, emb, ts, mem, lut, Wt, bt, bih, bhh,
                                    bfragH, bfragL, winner, out0, out1, N, nchunks);

    long vec = (long)NUM_NODES * 16;
    k_fill<<<(int)((vec + 255) / 256), 256, 0, stream>>>(
        winner, (const float4*)mem, (float4*)out1, NUM_NODES);

    k_time<<<(NUM_NODES + 255) / 256, 256, 0, stream>>>(out2, ts, lut, NUM_NODES);
}

// Round 5
// 244.763 us; speedup vs baseline: 6.2007x; 1.3065x over previous
//
#include <hip/hip_runtime.h>
#include <cstdint>
#include <cstddef>

#define DD 64

typedef float    f32x4  __attribute__((ext_vector_type(4)));
typedef _Float16 f16x8  __attribute__((ext_vector_type(8)));
typedef _Float16 f16x4  __attribute__((ext_vector_type(4)));

__device__ __forceinline__ float sigmoidf_(float x) {
    return 1.0f / (1.0f + __expf(-x));
}
__device__ __forceinline__ float tanh_fast(float x) {
    float ax = fabsf(x);
    float t = 1.0f - 2.0f / (1.0f + __expf(2.0f * ax));
    return copysignf(t, x);
}
__device__ __forceinline__ f32x4 MFMA(f32x4 c, f16x8 a, f16x8 b) {
    return __builtin_amdgcn_mfma_f32_16x16x32_f16(a, b, c, 0, 0, 0);
}

// ---------------- winner voting (winner[] lives in out2 region) ----------------
__global__ void k_init(int* __restrict__ winner, int num_nodes) {
    int i = blockIdx.x * blockDim.x + threadIdx.x;
    if (i < num_nodes) winner[i] = -1;
}
__global__ void k_vote(const int* __restrict__ ids, int* __restrict__ winner, int n) {
    int i = blockIdx.x * blockDim.x + threadIdx.x;
    if (i < n) atomicMax(&winner[ids[i]], i);
}

// ---------------- build B fragments (hi/lo split fp16) into ws ----------------
// Conceptual B[128][256]: cols 0..63 r-gate (K: x then h), 64..127 z-gate,
// 128..191 i_n (x only), 192..255 h_n (h only).
// Fragment f = g*4+s (g=tile 0..15, s=K-step 0..3); lane l holds
// B[s*32+(l>>4)*8+j][g*16+(l&15)], j=0..7, packed 8 fp16 = 16B.
__global__ void k_prep(const float* __restrict__ Wih, const float* __restrict__ Whh,
                       _Float16* __restrict__ bhi, _Float16* __restrict__ blo)
{
    int f = blockIdx.x;        // 0..63
    int l = threadIdx.x;       // 0..63
    int g = f >> 2, s = f & 3;
    int c = g * 16 + (l & 15);
    int grp = c >> 6, d = c & 63;
    int kbase = s * 32 + (l >> 4) * 8;
    int row = (grp == 0) ? d : (grp == 1) ? 64 + d : 128 + d;

    f16x8 hv, lv;
    for (int j = 0; j < 8; ++j) {
        int k = kbase + j;
        float v;
        if (grp <= 1)      v = (k < 64) ? Wih[row * 64 + k] : Whh[row * 64 + (k - 64)];
        else if (grp == 2) v = (k < 64) ? Wih[row * 64 + k] : 0.0f;
        else               v = (k < 64) ? 0.0f : Whh[row * 64 + (k - 64)];
        _Float16 h = (_Float16)v;
        hv[j] = h;
        lv[j] = (_Float16)(v - (float)h);
    }
    size_t off = ((size_t)f * 64 + l);
    ((f16x8*)bhi)[off] = hv;
    ((f16x8*)blo)[off] = lv;
}

// ---------------- main GRU kernel (MFMA, asymmetric split-fp16) ----------------
// One 64-event chunk per block; x split hi/lo, h plain fp16.
__global__ __launch_bounds__(256, 3) void k_gru(
    const int* __restrict__ ids,
    const float* __restrict__ emb,
    const float* __restrict__ ts,
    const float* __restrict__ mem,
    const float* __restrict__ lut,
    const float* __restrict__ Wt,
    const float* __restrict__ bt,
    const float* __restrict__ bih,
    const float* __restrict__ bhh,
    const _Float16* __restrict__ bhi,
    const _Float16* __restrict__ blo,
    const int* __restrict__ winner,
    float* __restrict__ out0,
    float* __restrict__ out1,
    int n)
{
    __shared__ _Float16 xhh[64][136];   // hi plane: [event][k], k<64 x_hi, k>=64 h
    __shared__ _Float16 xhl[64][72];    // lo plane: x_lo only (k<64)
    __shared__ int sid[64];
    __shared__ int swin[64];

    const int w    = threadIdx.x >> 6;
    const int l    = threadIdx.x & 63;
    const int col  = l & 15;
    const int rowg = l >> 4;
    const int d    = w * 16 + col;      // output dim this lane owns in epilogue

    const float bR  = bih[d] + bhh[d];
    const float bZ  = bih[64 + d] + bhh[64 + d];
    const float bIN = bih[128 + d];
    const float bHN = bhh[128 + d];

    // persistent B fragments for this wave's 4 gate tiles (L2-resident)
    const f16x8* H = (const f16x8*)bhi;
    const f16x8* L = (const f16x8*)blo;
    f16x8 BRh0 = H[(size_t)(w * 4 + 0) * 64 + l];
    f16x8 BRh1 = H[(size_t)(w * 4 + 1) * 64 + l];
    f16x8 BRh2 = H[(size_t)(w * 4 + 2) * 64 + l];
    f16x8 BRh3 = H[(size_t)(w * 4 + 3) * 64 + l];
    f16x8 BRl0 = L[(size_t)(w * 4 + 0) * 64 + l];
    f16x8 BRl1 = L[(size_t)(w * 4 + 1) * 64 + l];
    f16x8 BZh0 = H[(size_t)((4 + w) * 4 + 0) * 64 + l];
    f16x8 BZh1 = H[(size_t)((4 + w) * 4 + 1) * 64 + l];
    f16x8 BZh2 = H[(size_t)((4 + w) * 4 + 2) * 64 + l];
    f16x8 BZh3 = H[(size_t)((4 + w) * 4 + 3) * 64 + l];
    f16x8 BZl0 = L[(size_t)((4 + w) * 4 + 0) * 64 + l];
    f16x8 BZl1 = L[(size_t)((4 + w) * 4 + 1) * 64 + l];
    f16x8 BIh0 = H[(size_t)((8 + w) * 4 + 0) * 64 + l];
    f16x8 BIh1 = H[(size_t)((8 + w) * 4 + 1) * 64 + l];
    f16x8 BIl0 = L[(size_t)((8 + w) * 4 + 0) * 64 + l];
    f16x8 BIl1 = L[(size_t)((8 + w) * 4 + 1) * 64 + l];
    f16x8 BHh0 = H[(size_t)((12 + w) * 4 + 2) * 64 + l];
    f16x8 BHh1 = H[(size_t)((12 + w) * 4 + 3) * 64 + l];

    const f32x4 wt4 = ((const f32x4*)Wt)[col];
    const f32x4 bt4 = ((const f32x4*)bt)[col];

    const long base = (long)blockIdx.x * 64;

    // ---- phase A: lanes 0..15 fetch per-event scalars in parallel ----
    float dtA = 0.f; int idA = 0;
    if (l < 16) {
        long ev = base + w * 16 + l;
        int id = 0, win = 0; float dt = 0.f;
        if (ev < n) {
            id = ids[ev];
            dt = ts[ev] - lut[id];
            win = (winner[id] == (int)ev) ? 1 : 0;
        }
        idA = id; dtA = dt;
        sid[w * 16 + l] = id;
        swin[w * 16 + l] = win;
    }

    // ---- phase B: 4 iterations of 16B loads; each lane does 4 dims of 1 event ----
    #pragma unroll
    for (int it = 0; it < 4; ++it) {
        int  e_loc = it * 4 + rowg;           // 0..15
        int  r     = w * 16 + e_loc;
        long ev    = base + r;
        int   id = __shfl(idA, e_loc);
        float dt = __shfl(dtA, e_loc);
        f32x4 xv = {0.f, 0.f, 0.f, 0.f};
        f32x4 hv = {0.f, 0.f, 0.f, 0.f};
        if (ev < n) {
            xv = __builtin_nontemporal_load(&((const f32x4*)emb)[(size_t)ev * 16 + col]);
            hv = ((const f32x4*)mem)[(size_t)id * 16 + col];
            xv.x = fmaf(dt, wt4.x, xv.x + bt4.x);
            xv.y = fmaf(dt, wt4.y, xv.y + bt4.y);
            xv.z = fmaf(dt, wt4.z, xv.z + bt4.z);
            xv.w = fmaf(dt, wt4.w, xv.w + bt4.w);
        }
        f16x4 xh, xl, hh;
        {
            _Float16 a;
            a = (_Float16)xv.x; xh[0] = a; xl[0] = (_Float16)(xv.x - (float)a);
            a = (_Float16)xv.y; xh[1] = a; xl[1] = (_Float16)(xv.y - (float)a);
            a = (_Float16)xv.z; xh[2] = a; xl[2] = (_Float16)(xv.z - (float)a);
            a = (_Float16)xv.w; xh[3] = a; xl[3] = (_Float16)(xv.w - (float)a);
            hh[0] = (_Float16)hv.x;
            hh[1] = (_Float16)hv.y;
            hh[2] = (_Float16)hv.z;
            hh[3] = (_Float16)hv.w;
        }
        *(f16x4*)&xhh[r][col * 4]      = xh;
        *(f16x4*)&xhl[r][col * 4]      = xl;
        *(f16x4*)&xhh[r][64 + col * 4] = hh;
    }
    __syncthreads();

    // ---- 4 M-tiles of 16 events each ----
    #pragma unroll
    for (int mt = 0; mt < 4; ++mt) {
        const int arow = mt * 16 + col;
        const int k0   = rowg * 8;
        f16x8 Ah0 = *(const f16x8*)&xhh[arow][0 * 32 + k0];
        f16x8 Ah1 = *(const f16x8*)&xhh[arow][1 * 32 + k0];
        f16x8 Ah2 = *(const f16x8*)&xhh[arow][2 * 32 + k0];
        f16x8 Ah3 = *(const f16x8*)&xhh[arow][3 * 32 + k0];
        f16x8 Al0 = *(const f16x8*)&xhl[arow][0 * 32 + k0];
        f16x8 Al1 = *(const f16x8*)&xhl[arow][1 * 32 + k0];

        f32x4 aR = {0,0,0,0}, aZ = {0,0,0,0}, aI = {0,0,0,0}, aH = {0,0,0,0};
        __builtin_amdgcn_s_setprio(1);
        // r-gate: x part (s=0,1) 3-term, h part (s=2,3) 1-term
        aR = MFMA(aR, Ah0, BRh0); aR = MFMA(aR, Ah0, BRl0); aR = MFMA(aR, Al0, BRh0);
        aR = MFMA(aR, Ah1, BRh1); aR = MFMA(aR, Ah1, BRl1); aR = MFMA(aR, Al1, BRh1);
        aR = MFMA(aR, Ah2, BRh2); aR = MFMA(aR, Ah3, BRh3);
        // z-gate
        aZ = MFMA(aZ, Ah0, BZh0); aZ = MFMA(aZ, Ah0, BZl0); aZ = MFMA(aZ, Al0, BZh0);
        aZ = MFMA(aZ, Ah1, BZh1); aZ = MFMA(aZ, Ah1, BZl1); aZ = MFMA(aZ, Al1, BZh1);
        aZ = MFMA(aZ, Ah2, BZh2); aZ = MFMA(aZ, Ah3, BZh3);
        // i_n: x only
        aI = MFMA(aI, Ah0, BIh0); aI = MFMA(aI, Ah0, BIl0); aI = MFMA(aI, Al0, BIh0);
        aI = MFMA(aI, Ah1, BIh1); aI = MFMA(aI, Ah1, BIl1); aI = MFMA(aI, Al1, BIh1);
        // h_n: h only
        aH = MFMA(aH, Ah2, BHh0); aH = MFMA(aH, Ah3, BHh1);
        __builtin_amdgcn_s_setprio(0);

        // ---- epilogue: gates, output, fused winner scatter ----
        #pragma unroll
        for (int r = 0; r < 4; ++r) {
            int  eloc = mt * 16 + rowg * 4 + r;
            long ev   = base + eloc;
            if (ev < n) {
                float rr = sigmoidf_(aR[r] + bR);
                float zz = sigmoidf_(aZ[r] + bZ);
                float nn = tanh_fast(aI[r] + bIN + rr * (aH[r] + bHN));
                float hv = (float)xhh[eloc][64 + d];
                float o  = (1.f - zz) * nn + zz * hv;
                __builtin_nontemporal_store(o, &out0[(size_t)ev * 64 + d]);
                if (swin[eloc])
                    __builtin_nontemporal_store(o, &out1[(size_t)sid[eloc] * 64 + d]);
            }
        }
    }
}

// out1 rows for untouched nodes (winner<0): copy from node_memory
__global__ void k_fill(const int* __restrict__ winner,
                       const f32x4* __restrict__ mem4,
                       f32x4* __restrict__ out14,
                       int num_nodes)
{
    int idx = blockIdx.x * blockDim.x + threadIdx.x;
    if (idx >= num_nodes * 16) return;
    int nidx = idx >> 4;
    if (winner[nidx] < 0) {
        f32x4 v = __builtin_nontemporal_load(&mem4[idx]);
        __builtin_nontemporal_store(v, &out14[idx]);
    }
}

// out2[n] = winner>=0 ? ts[winner] : lut[n]; winner stored IN out2, self-slot RMW
__global__ void k_time(float* out2,
                       const float* __restrict__ ts,
                       const float* __restrict__ lut,
                       int num_nodes)
{
    int i = blockIdx.x * blockDim.x + threadIdx.x;
    if (i < num_nodes) {
        int wv = reinterpret_cast<const int*>(out2)[i];
        out2[i] = (wv >= 0) ? ts[wv] : lut[i];
    }
}

extern "C" void kernel_launch(void* const* d_in, const int* in_sizes, int n_in,
                              void* d_out, int out_size, void* d_ws, size_t ws_size,
                              hipStream_t stream) {
    const int*   ids = (const int*)  d_in[0];
    const float* emb = (const float*)d_in[1];
    const float* ts  = (const float*)d_in[2];
    const float* mem = (const float*)d_in[3];
    const float* lut = (const float*)d_in[4];
    const float* Wt  = (const float*)d_in[5];
    const float* bt  = (const float*)d_in[6];
    const float* Wih = (const float*)d_in[7];
    const float* Whh = (const float*)d_in[8];
    const float* bih = (const float*)d_in[9];
    const float* bhh = (const float*)d_in[10];

    const int N         = in_sizes[0];
    const int NUM_NODES = in_sizes[4];

    float* out0 = (float*)d_out;                    // [N,64]
    float* out1 = out0 + (size_t)N * DD;            // [NUM_NODES,64]
    float* out2 = out1 + (size_t)NUM_NODES * DD;    // [NUM_NODES]
    int*   winner = (int*)out2;

    _Float16* bfragH = (_Float16*)d_ws;             // 64 KB
    _Float16* bfragL = bfragH + 64 * 64 * 8;        // 64 KB

    k_init<<<(NUM_NODES + 255) / 256, 256, 0, stream>>>(winner, NUM_NODES);
    k_vote<<<(N + 255) / 256, 256, 0, stream>>>(ids, winner, N);
    k_prep<<<64, 64, 0, stream>>>(Wih, Whh, bfragH, bfragL);

    int nchunks = (N + 63) / 64;
    k_gru<<<nchunks, 256, 0, stream>>>(ids, emb, ts, mem, lut, Wt, bt, bih, bhh,
                                       bfragH, bfragL, winner, out0, out1, N);

    long vec = (long)NUM_NODES * 16;
    k_fill<<<(int)((vec + 255) / 256), 256, 0, stream>>>(
        winner, (const f32x4*)mem, (f32x4*)out1, NUM_NODES);

    k_time<<<(NUM_NODES + 255) / 256, 256, 0, stream>>>(out2, ts, lut, NUM_NODES);
}